// Round 9
// baseline (162.325 us; speedup 1.0000x reference)
//
#include <hip/hip_runtime.h>
#include <hip/hip_bf16.h>
#include <cstdint>

#define NN 100000
#define DEG 16
#define FF 256
#define UU 128
#define SLICE_BYTES 3200000   // NN * 16 dims * 2B
#define NTILE 3125            // NN / 32
#define GEMM_BLOCKS 512       // persistent blocks (2 per CU)

typedef __attribute__((ext_vector_type(8))) short short8;
typedef __attribute__((ext_vector_type(4))) float f32x4;
typedef __attribute__((ext_vector_type(4))) unsigned int u32x4;

#define PIN8(a,b,c,d,e,f,g,h) asm volatile("" : "+v"(a),"+v"(b),"+v"(c),"+v"(d),"+v"(e),"+v"(f),"+v"(g),"+v"(h))

__device__ __forceinline__ unsigned short f2bf(float x) {
    uint32_t u = __builtin_bit_cast(uint32_t, x);
    uint32_t r = (u + 0x7fffu + ((u >> 16) & 1u)) >> 16;
    return (unsigned short)r;
}
__device__ __forceinline__ float bf2f(unsigned short b) {
    return __builtin_bit_cast(float, (uint32_t)b << 16);
}
__device__ __forceinline__ uint32_t cvt_pk_bf16(float lo, float hi) {
    uint32_t r;
    asm("v_cvt_pk_bf16_f32 %0, %1, %2" : "=v"(r) : "v"(lo), "v"(hi));
    return r;
}
#define GLL16(gp, lp) __builtin_amdgcn_global_load_lds( \
    (const __attribute__((address_space(1))) void*)(gp), \
    (__attribute__((address_space(3))) void*)(lp), 16, 0, 0)

// Pre-kernel: W [256][128] f32 -> Wt [128][256] bf16 (transposed, 64 KB, L2-hot).
__global__ void k_convW(const float* __restrict__ W, unsigned short* __restrict__ Wt) {
    int i = blockIdx.x * 256 + threadIdx.x;  // 32768 elements
    int k = i >> 7, c = i & 127;
    Wt[c * 256 + k] = f2bf(W[i]);
}

// GEMM: h = ns @ W via bf16 MFMA. PERSISTENT: 512 blocks, each grid-strides
// over 32-row tiles with DOUBLE-BUFFERED global_load_lds staging (hardware-
// async: the compiler cannot serialize it — rounds 3..8 showed it rolls any
// register-batch back into a load->use chain). Stage of tile t+1 overlaps
// compute+epilogue of tile t; raw s_barrier + manual waitcnt so the epilogue
// barrier does NOT drain the in-flight stage. B frags loaded once per block.
__global__ __launch_bounds__(256, 2) void k_gemm(
    const float* __restrict__ ns, const unsigned short* __restrict__ Wt,
    const float* __restrict__ ka, unsigned short* __restrict__ hbs,
    float* __restrict__ a_src, float* __restrict__ a_dst)
{
    __shared__ char smem[2 * 32768 + 32 * 136 * 2 + 1024];
    unsigned short* Hs = (unsigned short*)(smem + 65536);   // Ht[32][136]
    float* ka_s = (float*)(smem + 65536 + 8704);
    const int t = threadIdx.x;
    const int lane = t & 63;
    const int w = t >> 6;
    const int lrow = lane & 15;
    const int khalf = lane >> 4;

    ka_s[t] = ka[t];

    // ---- B fragments (once per persistent block): (lane,e)->k = khalf*8+ks*32+e ----
    short8 bfrag[2][8];
    {
        const int col0 = w * 32 + lrow;
        #pragma unroll
        for (int nt = 0; nt < 2; ++nt) {
            const unsigned short* wp = Wt + (size_t)(col0 + nt * 16) * 256 + khalf * 8;
            #pragma unroll
            for (int ks = 0; ks < 8; ++ks)
                bfrag[nt][ks] = *(const short8*)(wp + ks * 32);
        }
    }
    PIN8(bfrag[0][0], bfrag[0][1], bfrag[0][2], bfrag[0][3],
         bfrag[0][4], bfrag[0][5], bfrag[0][6], bfrag[0][7]);
    PIN8(bfrag[1][0], bfrag[1][1], bfrag[1][2], bfrag[1][3],
         bfrag[1][4], bfrag[1][5], bfrag[1][6], bfrag[1][7]);

    // stage tile -> buf: wave w stages rows [w*8, w*8+8), 1 KB (one row) per
    // issue; global source granule pre-XOR'd (rule 21: LDS dest stays linear).
    auto stage = [&](int tile, char* buf) {
        #pragma unroll
        for (int i = 0; i < 8; ++i) {
            const int rr = w * 8 + i;
            const float* src = ns + (size_t)(tile * 32 + rr) * FF + ((lane ^ (rr & 7)) * 4);
            GLL16(src, buf + rr * 1024);
        }
    };

    int cur = 0;
    stage(blockIdx.x, smem);   // prologue: tile0 -> buf0

    for (int tl = blockIdx.x; tl < NTILE; tl += GEMM_BLOCKS) {
        // barrier A: buf[cur] staged (per-wave vmcnt drain + all waves);
        // also separates prev iter's Hs reads from this iter's Hs writes.
        asm volatile("s_waitcnt vmcnt(0) lgkmcnt(0)" ::: "memory");
        __builtin_amdgcn_sched_barrier(0);
        __builtin_amdgcn_s_barrier();

        const int nxt = tl + GEMM_BLOCKS;
        if (nxt < NTILE) stage(nxt, smem + (cur ^ 1) * 32768);
        __builtin_amdgcn_sched_barrier(0);   // keep stage issues ahead of compute

        // ---- compute tile from buf[cur]: 8 ks x (4 b128 + 8 cvt_pk + 4 MFMA) ----
        const char* buf = smem + cur * 32768;
        f32x4 acc[2][2];
        #pragma unroll
        for (int mt = 0; mt < 2; ++mt)
            #pragma unroll
            for (int nt = 0; nt < 2; ++nt)
                acc[mt][nt] = (f32x4){0.f, 0.f, 0.f, 0.f};

        #pragma unroll
        for (int ks = 0; ks < 8; ++ks) {
            short8 a[2];
            #pragma unroll
            for (int mt = 0; mt < 2; ++mt) {
                const int row = mt * 16 + lrow;
                const int kg = ks * 8 + khalf * 2;       // 16B granule index
                const char* rb = buf + row * 1024;
                f32x4 x0 = *(const f32x4*)(rb + ((kg ^ (row & 7)) * 16));
                f32x4 x1 = *(const f32x4*)(rb + (((kg + 1) ^ (row & 7)) * 16));
                u32x4 u;
                u[0] = cvt_pk_bf16(x0[0], x0[1]);
                u[1] = cvt_pk_bf16(x0[2], x0[3]);
                u[2] = cvt_pk_bf16(x1[0], x1[1]);
                u[3] = cvt_pk_bf16(x1[2], x1[3]);
                a[mt] = __builtin_bit_cast(short8, u);
            }
            #pragma unroll
            for (int mt = 0; mt < 2; ++mt)
                #pragma unroll
                for (int nt = 0; nt < 2; ++nt)
                    acc[mt][nt] = __builtin_amdgcn_mfma_f32_16x16x32_bf16(
                        a[mt], bfrag[nt][ks], acc[mt][nt], 0, 0, 0);
        }

        // ---- epilogue: acc -> Ht (stride 136 breaks bank aliasing) ----
        {
            const int wcol = w * 32;
            #pragma unroll
            for (int mt = 0; mt < 2; ++mt)
                #pragma unroll
                for (int nt = 0; nt < 2; ++nt)
                    #pragma unroll
                    for (int r = 0; r < 4; ++r) {
                        int row = mt * 16 + khalf * 4 + r;
                        int col = wcol + nt * 16 + lrow;
                        Hs[row * 136 + col] = f2bf(acc[mt][nt][r]);
                    }
        }
        // barrier B: LDS-only drain — does NOT wait vmcnt, stage stays in flight
        asm volatile("s_waitcnt lgkmcnt(0)" ::: "memory");
        __builtin_amdgcn_sched_barrier(0);
        __builtin_amdgcn_s_barrier();

        // ---- slice-major hbs store + attention dots (8 threads/row, 16 dims) ----
        {
            const int row = t >> 3, q8 = t & 7;            // q8 == slice index
            const int gr = tl * 32 + row;
            short8 hv0 = *(const short8*)(Hs + row * 136 + q8 * 16);
            short8 hv1 = *(const short8*)(Hs + row * 136 + q8 * 16 + 8);
            float ps = 0.f, pd = 0.f;
            #pragma unroll
            for (int e = 0; e < 8; ++e) {
                int c = q8 * 16 + e;
                ps = fmaf(bf2f((unsigned short)hv0[e]), ka_s[c], ps);
                pd = fmaf(bf2f((unsigned short)hv0[e]), ka_s[UU + c], pd);
                ps = fmaf(bf2f((unsigned short)hv1[e]), ka_s[c + 8], ps);
                pd = fmaf(bf2f((unsigned short)hv1[e]), ka_s[UU + c + 8], pd);
            }
            char* base = (char*)hbs + (size_t)q8 * SLICE_BYTES + (size_t)gr * 32;
            *(short8*)(base) = hv0;
            *(short8*)(base + 16) = hv1;
            ps += __shfl_xor(ps, 1, 64); ps += __shfl_xor(ps, 2, 64); ps += __shfl_xor(ps, 4, 64);
            pd += __shfl_xor(pd, 1, 64); pd += __shfl_xor(pd, 2, 64); pd += __shfl_xor(pd, 4, 64);
            if (q8 == 0) { a_src[gr] = ps; a_dst[gr] = pd; }
        }
        cur ^= 1;
    }
}

// Edge kernel: scores + per-node softmax -> packed nd[e] = (dst<<15) | norm_q15.
__global__ __launch_bounds__(256, 8) void k_edge(
    const int* __restrict__ edges, const float* __restrict__ ew,
    const float* __restrict__ a_src, const float* __restrict__ a_dst,
    uint32_t* __restrict__ nd)
{
    const int ei = blockIdx.x * 256 + threadIdx.x;
    const int n = ei >> 4;
    const int dst = edges[2 * ei + 1];
    const float w = ew[ei];
    const float x0 = w * (a_src[n] + a_dst[dst]);
    float x = x0 > 0.f ? x0 : 0.2f * x0;        // leaky_relu, slope 0.2
    x = fminf(2.f, fmaxf(-2.f, x));             // clip
    const float s = __expf(x);

    float ssum = s;                              // xor masks <16 stay in-group
    ssum += __shfl_xor(ssum, 1, 64);
    ssum += __shfl_xor(ssum, 2, 64);
    ssum += __shfl_xor(ssum, 4, 64);
    ssum += __shfl_xor(ssum, 8, 64);
    const float norm = s / ssum;

    uint32_t q15 = (uint32_t)(norm * 32768.f + 0.5f);
    if (q15 > 32767u) q15 = 32767u;
    nd[ei] = ((uint32_t)dst << 15) | q15;
}

// Aggregation, dim-sliced + XCD-pinned: slice = bid & 7 (consecutive blockIdx
// round-robin XCDs -> all blocks of slice s run on XCD s, whose private L2
// holds exactly that slice's 3.2 MB hbs region -> L2-resident gather).
// ZERO LDS, ~50 VGPR -> full occupancy is the latency fix (r8: 64KB LDS
// capped us at 8 waves/CU). 4 lanes per node: lane q reads its 4 edges'
// 32B slice-rows, accumulates 16 dims, quad shfl-reduce, writes float4.
__global__ __launch_bounds__(256, 8) void k_agg(
    const uint32_t* __restrict__ nd, const unsigned short* __restrict__ hbs,
    float* __restrict__ out)
{
    const int t = threadIdx.x;
    const int slice = blockIdx.x & 7;
    const int nb = blockIdx.x >> 3;
    const int nl = t >> 2;         // node within block (64/block)
    const int q = t & 3;           // quad lane: edges [q*4, q*4+4)
    const int n = nb * 64 + nl;    // 1563*64 = 100032 -> guard
    const bool valid = n < NN;
    const int nc = valid ? n : NN - 1;

    const u32x4 ndv = *(const u32x4*)(nd + (size_t)nc * DEG + q * 4);
    const char* hs = (const char*)hbs + (size_t)slice * SLICE_BYTES;

    float acc[16];
    #pragma unroll
    for (int d = 0; d < 16; ++d) acc[d] = 0.f;

    #pragma unroll
    for (int j = 0; j < 4; ++j) {
        const uint32_t v = ndv[j];
        const char* p = hs + ((size_t)(v >> 15) << 5);   // dst * 32B
        const u32x4 r0 = *(const u32x4*)p;
        const u32x4 r1 = *(const u32x4*)(p + 16);
        const float nf = (float)(v & 32767u) * (1.f / 32768.f);
        #pragma unroll
        for (int d = 0; d < 4; ++d) {
            acc[2 * d]     = fmaf(nf, __builtin_bit_cast(float, r0[d] << 16), acc[2 * d]);
            acc[2 * d + 1] = fmaf(nf, __builtin_bit_cast(float, r0[d] & 0xffff0000u), acc[2 * d + 1]);
            acc[8 + 2 * d]     = fmaf(nf, __builtin_bit_cast(float, r1[d] << 16), acc[8 + 2 * d]);
            acc[8 + 2 * d + 1] = fmaf(nf, __builtin_bit_cast(float, r1[d] & 0xffff0000u), acc[8 + 2 * d + 1]);
        }
    }

    // quad reduce: after xor 1 & 2, all 4 lanes hold the node's 16 sums
    #pragma unroll
    for (int d = 0; d < 16; ++d) {
        acc[d] += __shfl_xor(acc[d], 1, 64);
        acc[d] += __shfl_xor(acc[d], 2, 64);
    }

    if (valid) {
        float4 o;
        o.x = acc[q * 4]; o.y = acc[q * 4 + 1]; o.z = acc[q * 4 + 2]; o.w = acc[q * 4 + 3];
        *(float4*)(out + (size_t)n * UU + slice * 16 + q * 4) = o;
    }
}

extern "C" void kernel_launch(void* const* d_in, const int* in_sizes, int n_in,
                              void* d_out, int out_size, void* d_ws, size_t ws_size,
                              hipStream_t stream) {
    const float* ns    = (const float*)d_in[0];  // [1, N, 256] f32
    const int*   edges = (const int*)d_in[1];    // [1, E, 2] i32, src sorted
    const float* ew    = (const float*)d_in[2];  // [1, E] f32
    const float* W     = (const float*)d_in[3];  // [256, 128] f32
    const float* ka    = (const float*)d_in[4];  // [256, 1] f32
    float* out = (float*)d_out;                  // [N, 128] f32

    char* ws = (char*)d_ws;
    unsigned short* hbs = (unsigned short*)ws;                   // 8 x 3.2 MB slice-major
    float* a_src = (float*)(ws + (size_t)8 * SLICE_BYTES);       // N f32
    float* a_dst = a_src + NN;                                   // N f32
    unsigned short* Wt = (unsigned short*)(ws + (size_t)8 * SLICE_BYTES + 2 * (size_t)NN * 4);  // 64 KB
    uint32_t* nd = (uint32_t*)(ws + (size_t)8 * SLICE_BYTES + 2 * (size_t)NN * 4 + 65536);      // E u32 = 6.4 MB

    k_convW<<<FF * UU / 256, 256, 0, stream>>>(W, Wt);                        // 128 blocks
    k_gemm<<<GEMM_BLOCKS, 256, 0, stream>>>(ns, Wt, ka, hbs, a_src, a_dst);   // 512 persistent
    k_edge<<<NN * DEG / 256, 256, 0, stream>>>(edges, ew, a_src, a_dst, nd);  // 6250 blocks
    k_agg<<<8 * 1563, 256, 0, stream>>>(nd, hbs, out);                        // 12504 blocks
}

// Round 10
// 102.332 us; speedup vs baseline: 1.5863x; 1.5863x over previous
//
#include <hip/hip_runtime.h>
#include <hip/hip_bf16.h>
#include <cstdint>

#define NN 100000
#define DEG 16
#define FF 256
#define UU 128
#define NTILE 3125            // NN / 32
#define GEMM_BLOCKS 512       // persistent blocks (2 per CU)

typedef __attribute__((ext_vector_type(8))) short short8;
typedef __attribute__((ext_vector_type(4))) float f32x4;
typedef __attribute__((ext_vector_type(4))) unsigned int u32x4;

#define PIN8(a,b,c,d,e,f,g,h) asm volatile("" : "+v"(a),"+v"(b),"+v"(c),"+v"(d),"+v"(e),"+v"(f),"+v"(g),"+v"(h))

__device__ __forceinline__ unsigned short f2bf(float x) {
    uint32_t u = __builtin_bit_cast(uint32_t, x);
    uint32_t r = (u + 0x7fffu + ((u >> 16) & 1u)) >> 16;
    return (unsigned short)r;
}
__device__ __forceinline__ float bf2f(unsigned short b) {
    return __builtin_bit_cast(float, (uint32_t)b << 16);
}
__device__ __forceinline__ uint32_t cvt_pk_bf16(float lo, float hi) {
    uint32_t r;
    asm("v_cvt_pk_bf16_f32 %0, %1, %2" : "=v"(r) : "v"(lo), "v"(hi));
    return r;
}
#define GLL16(gp, lp) __builtin_amdgcn_global_load_lds( \
    (const __attribute__((address_space(1))) void*)(gp), \
    (__attribute__((address_space(3))) void*)(lp), 16, 0, 0)

// Pre-kernel: W [256][128] f32 -> Wt [128][256] bf16 (transposed, 64 KB, L2-hot).
__global__ void k_convW(const float* __restrict__ W, unsigned short* __restrict__ Wt) {
    int i = blockIdx.x * 256 + threadIdx.x;  // 32768 elements
    int k = i >> 7, c = i & 127;
    Wt[c * 256 + k] = f2bf(W[i]);
}

// GEMM: h = ns @ W via bf16 MFMA. PERSISTENT: 512 blocks grid-striding over
// 32-row tiles with DOUBLE-BUFFERED global_load_lds staging (hardware-async;
// proven ~33us in r9). Stage of tile t+1 overlaps compute+epilogue of tile t;
// raw s_barrier + manual waitcnt so the epilogue barrier does NOT drain the
// in-flight stage. B frags loaded once per block. Epilogue: ROW-MAJOR hb
// store (r10: agg gathers full 256B rows again) + fused attention dots.
__global__ __launch_bounds__(256, 2) void k_gemm(
    const float* __restrict__ ns, const unsigned short* __restrict__ Wt,
    const float* __restrict__ ka, unsigned short* __restrict__ hb,
    float* __restrict__ a_src, float* __restrict__ a_dst)
{
    __shared__ char smem[2 * 32768 + 32 * 136 * 2 + 1024];
    unsigned short* Hs = (unsigned short*)(smem + 65536);   // Ht[32][136]
    float* ka_s = (float*)(smem + 65536 + 8704);
    const int t = threadIdx.x;
    const int lane = t & 63;
    const int w = t >> 6;
    const int lrow = lane & 15;
    const int khalf = lane >> 4;

    ka_s[t] = ka[t];

    // ---- B fragments (once per persistent block): (lane,e)->k = khalf*8+ks*32+e ----
    short8 bfrag[2][8];
    {
        const int col0 = w * 32 + lrow;
        #pragma unroll
        for (int nt = 0; nt < 2; ++nt) {
            const unsigned short* wp = Wt + (size_t)(col0 + nt * 16) * 256 + khalf * 8;
            #pragma unroll
            for (int ks = 0; ks < 8; ++ks)
                bfrag[nt][ks] = *(const short8*)(wp + ks * 32);
        }
    }
    PIN8(bfrag[0][0], bfrag[0][1], bfrag[0][2], bfrag[0][3],
         bfrag[0][4], bfrag[0][5], bfrag[0][6], bfrag[0][7]);
    PIN8(bfrag[1][0], bfrag[1][1], bfrag[1][2], bfrag[1][3],
         bfrag[1][4], bfrag[1][5], bfrag[1][6], bfrag[1][7]);

    // stage tile -> buf: wave w stages rows [w*8, w*8+8), 1 KB (one row) per
    // issue; global source granule pre-XOR'd (rule 21: LDS dest stays linear).
    auto stage = [&](int tile, char* buf) {
        #pragma unroll
        for (int i = 0; i < 8; ++i) {
            const int rr = w * 8 + i;
            const float* src = ns + (size_t)(tile * 32 + rr) * FF + ((lane ^ (rr & 7)) * 4);
            GLL16(src, buf + rr * 1024);
        }
    };

    int cur = 0;
    stage(blockIdx.x, smem);   // prologue: tile0 -> buf0

    for (int tl = blockIdx.x; tl < NTILE; tl += GEMM_BLOCKS) {
        // barrier A: buf[cur] staged (per-wave vmcnt drain + all waves);
        // also separates prev iter's Hs reads from this iter's Hs writes.
        asm volatile("s_waitcnt vmcnt(0) lgkmcnt(0)" ::: "memory");
        __builtin_amdgcn_sched_barrier(0);
        __builtin_amdgcn_s_barrier();

        const int nxt = tl + GEMM_BLOCKS;
        if (nxt < NTILE) stage(nxt, smem + (cur ^ 1) * 32768);
        __builtin_amdgcn_sched_barrier(0);   // keep stage issues ahead of compute

        // ---- compute tile from buf[cur]: 8 ks x (4 b128 + 8 cvt_pk + 4 MFMA) ----
        const char* buf = smem + cur * 32768;
        f32x4 acc[2][2];
        #pragma unroll
        for (int mt = 0; mt < 2; ++mt)
            #pragma unroll
            for (int nt = 0; nt < 2; ++nt)
                acc[mt][nt] = (f32x4){0.f, 0.f, 0.f, 0.f};

        #pragma unroll
        for (int ks = 0; ks < 8; ++ks) {
            short8 a[2];
            #pragma unroll
            for (int mt = 0; mt < 2; ++mt) {
                const int row = mt * 16 + lrow;
                const int kg = ks * 8 + khalf * 2;       // 16B granule index
                const char* rb = buf + row * 1024;
                f32x4 x0 = *(const f32x4*)(rb + ((kg ^ (row & 7)) * 16));
                f32x4 x1 = *(const f32x4*)(rb + (((kg + 1) ^ (row & 7)) * 16));
                u32x4 u;
                u[0] = cvt_pk_bf16(x0[0], x0[1]);
                u[1] = cvt_pk_bf16(x0[2], x0[3]);
                u[2] = cvt_pk_bf16(x1[0], x1[1]);
                u[3] = cvt_pk_bf16(x1[2], x1[3]);
                a[mt] = __builtin_bit_cast(short8, u);
            }
            #pragma unroll
            for (int mt = 0; mt < 2; ++mt)
                #pragma unroll
                for (int nt = 0; nt < 2; ++nt)
                    acc[mt][nt] = __builtin_amdgcn_mfma_f32_16x16x32_bf16(
                        a[mt], bfrag[nt][ks], acc[mt][nt], 0, 0, 0);
        }

        // ---- epilogue: acc -> Ht (stride 136 breaks bank aliasing) ----
        {
            const int wcol = w * 32;
            #pragma unroll
            for (int mt = 0; mt < 2; ++mt)
                #pragma unroll
                for (int nt = 0; nt < 2; ++nt)
                    #pragma unroll
                    for (int r = 0; r < 4; ++r) {
                        int row = mt * 16 + khalf * 4 + r;
                        int col = wcol + nt * 16 + lrow;
                        Hs[row * 136 + col] = f2bf(acc[mt][nt][r]);
                    }
        }
        // barrier B: LDS-only drain — does NOT wait vmcnt, stage stays in flight
        asm volatile("s_waitcnt lgkmcnt(0)" ::: "memory");
        __builtin_amdgcn_sched_barrier(0);
        __builtin_amdgcn_s_barrier();

        // ---- row-major hb store + attention dots (8 threads/row, 16 dims) ----
        {
            const int row = t >> 3, q8 = t & 7;
            const int gr = tl * 32 + row;
            short8 hv0 = *(const short8*)(Hs + row * 136 + q8 * 16);
            short8 hv1 = *(const short8*)(Hs + row * 136 + q8 * 16 + 8);
            float ps = 0.f, pd = 0.f;
            #pragma unroll
            for (int e = 0; e < 8; ++e) {
                int c = q8 * 16 + e;
                ps = fmaf(bf2f((unsigned short)hv0[e]), ka_s[c], ps);
                pd = fmaf(bf2f((unsigned short)hv0[e]), ka_s[UU + c], pd);
                ps = fmaf(bf2f((unsigned short)hv1[e]), ka_s[c + 8], ps);
                pd = fmaf(bf2f((unsigned short)hv1[e]), ka_s[UU + c + 8], pd);
            }
            short8* op = (short8*)(hb + (size_t)gr * UU + q8 * 16);
            op[0] = hv0;
            op[1] = hv1;
            ps += __shfl_xor(ps, 1, 64); ps += __shfl_xor(ps, 2, 64); ps += __shfl_xor(ps, 4, 64);
            pd += __shfl_xor(pd, 1, 64); pd += __shfl_xor(pd, 2, 64); pd += __shfl_xor(pd, 4, 64);
            if (q8 == 0) { a_src[gr] = ps; a_dst[gr] = pd; }
        }
        cur ^= 1;
    }
}

// Edge kernel: scores + per-node softmax -> packed nd[e] = (dst<<15) | norm_q15.
__global__ __launch_bounds__(256, 8) void k_edge(
    const int* __restrict__ edges, const float* __restrict__ ew,
    const float* __restrict__ a_src, const float* __restrict__ a_dst,
    uint32_t* __restrict__ nd)
{
    const int ei = blockIdx.x * 256 + threadIdx.x;
    const int n = ei >> 4;
    const int dst = edges[2 * ei + 1];
    const float w = ew[ei];
    const float x0 = w * (a_src[n] + a_dst[dst]);
    float x = x0 > 0.f ? x0 : 0.2f * x0;        // leaky_relu, slope 0.2
    x = fminf(2.f, fmaxf(-2.f, x));             // clip
    const float s = __expf(x);

    float ssum = s;                              // xor masks <16 stay in-group
    ssum += __shfl_xor(ssum, 1, 64);
    ssum += __shfl_xor(ssum, 2, 64);
    ssum += __shfl_xor(ssum, 4, 64);
    ssum += __shfl_xor(ssum, 8, 64);
    const float norm = s / ssum;

    uint32_t q15 = (uint32_t)(norm * 32768.f + 0.5f);
    if (q15 > 32767u) q15 = 32767u;
    nd[ei] = ((uint32_t)dst << 15) | q15;
}

// Aggregation (r10): 2-wave blocks, 4 nodes per wave, 16 lanes per node, lane
// q owns 16B of the row. Gather via global_load_lds with per-lane source
// addresses (hardware-async: r7 proved correctness; coalesced 4 rows/instr).
// Changes vs r7: 32 KB LDS blocks -> 5 blocks/CU -> 10 waves/CU (was 8),
// and PROGRESSIVE vmcnt drain: consume slot j at vmcnt(15-j) so the FMA of
// early slots overlaps the still-in-flight late loads (r7 stalled on vmcnt(0)).
__global__ __launch_bounds__(128) void k_agg(
    const uint32_t* __restrict__ nd, const unsigned short* __restrict__ hb,
    float* __restrict__ out)
{
    __shared__ char lds[2][16][1024];  // [wave][j][64 lanes * 16B] = 32 KB
    const int t = threadIdx.x;
    const int lane = t & 63;
    const int wv = t >> 6;
    const int g = lane >> 4;
    const int q = lane & 15;
    const int n = blockIdx.x * 8 + wv * 4 + g;   // 12500*8 = 100000 exact

    const uint32_t v = nd[(size_t)n * DEG + q];  // coalesced per 16-group
    const uint32_t dstB = (v >> 15) << 8;        // dst * 256 bytes
    const float normf = (float)(v & 32767u) * (1.f / 32768.f);
    const int gb = lane & 48;

    // issue all 16 gathers async: instr j loads edge j's row-segment for each
    // of the wave's 4 nodes (lane(g,q): src = hb + dst[g,j]*256 + q*16)
    const char* hbase = (const char*)hb + q * 16;
    #pragma unroll
    for (int j = 0; j < 16; ++j) {
        const uint32_t aj = __shfl(dstB, gb | j, 64);
        GLL16(hbase + aj, &lds[wv][j][0]);
    }

    float nf[16];
    #pragma unroll
    for (int j = 0; j < 16; ++j) nf[j] = __shfl(normf, gb | j, 64);

    float acc[8];
    #pragma unroll
    for (int d = 0; d < 8; ++d) acc[d] = 0.f;

    #pragma unroll
    for (int j = 0; j < 16; ++j) {
        asm volatile("s_waitcnt vmcnt(%0)" :: "n"(15 - j) : "memory");
        __builtin_amdgcn_sched_barrier(0);
        const u32x4 r = *(const u32x4*)(&lds[wv][j][0] + lane * 16);
        acc[0] = fmaf(nf[j], __builtin_bit_cast(float, r[0] << 16), acc[0]);
        acc[1] = fmaf(nf[j], __builtin_bit_cast(float, r[0] & 0xffff0000u), acc[1]);
        acc[2] = fmaf(nf[j], __builtin_bit_cast(float, r[1] << 16), acc[2]);
        acc[3] = fmaf(nf[j], __builtin_bit_cast(float, r[1] & 0xffff0000u), acc[3]);
        acc[4] = fmaf(nf[j], __builtin_bit_cast(float, r[2] << 16), acc[4]);
        acc[5] = fmaf(nf[j], __builtin_bit_cast(float, r[2] & 0xffff0000u), acc[5]);
        acc[6] = fmaf(nf[j], __builtin_bit_cast(float, r[3] << 16), acc[6]);
        acc[7] = fmaf(nf[j], __builtin_bit_cast(float, r[3] & 0xffff0000u), acc[7]);
    }

    float* op = out + (size_t)n * UU + q * 8;
    float4 o0, o1;
    o0.x = acc[0]; o0.y = acc[1]; o0.z = acc[2]; o0.w = acc[3];
    o1.x = acc[4]; o1.y = acc[5]; o1.z = acc[6]; o1.w = acc[7];
    *(float4*)op = o0;
    *(float4*)(op + 4) = o1;
}

extern "C" void kernel_launch(void* const* d_in, const int* in_sizes, int n_in,
                              void* d_out, int out_size, void* d_ws, size_t ws_size,
                              hipStream_t stream) {
    const float* ns    = (const float*)d_in[0];  // [1, N, 256] f32
    const int*   edges = (const int*)d_in[1];    // [1, E, 2] i32, src sorted
    const float* ew    = (const float*)d_in[2];  // [1, E] f32
    const float* W     = (const float*)d_in[3];  // [256, 128] f32
    const float* ka    = (const float*)d_in[4];  // [256, 1] f32
    float* out = (float*)d_out;                  // [N, 128] f32

    char* ws = (char*)d_ws;
    unsigned short* hb = (unsigned short*)ws;                    // N*128 bf16 = 25.6 MB
    float* a_src = (float*)(ws + (size_t)NN * UU * 2);           // N f32
    float* a_dst = a_src + NN;                                   // N f32
    unsigned short* Wt = (unsigned short*)(ws + (size_t)NN * UU * 2 + 2 * (size_t)NN * 4);  // 64 KB
    uint32_t* nd = (uint32_t*)(ws + (size_t)NN * UU * 2 + 2 * (size_t)NN * 4 + 65536);      // E u32 = 6.4 MB

    k_convW<<<FF * UU / 256, 256, 0, stream>>>(W, Wt);                        // 128 blocks
    k_gemm<<<GEMM_BLOCKS, 256, 0, stream>>>(ns, Wt, ka, hb, a_src, a_dst);    // 512 persistent
    k_edge<<<NN * DEG / 256, 256, 0, stream>>>(edges, ew, a_src, a_dst, nd);  // 6250 blocks
    k_agg<<<NN / 8, 128, 0, stream>>>(nd, hb, out);                           // 12500 blocks
}